// Round 8
// baseline (137.441 us; speedup 1.0000x reference)
//
#include <hip/hip_runtime.h>

// Problem constants (match reference): B=64, L=2048, H=256, K=32
#define LL 2048
#define BB 64
#define HH 256
#define KK 32

#define NB  1024   // 4 blocks/CU, 16 waves/CU
#define WPB 4      // waves per block

typedef __attribute__((ext_vector_type(8))) short  short8;   // 8 bf16 (4 VGPRs)
typedef __attribute__((ext_vector_type(4))) float  f32x4;

__device__ __forceinline__ float softplus_f(float x) {
    return x > 20.f ? x : __logf(1.f + __expf(x));
}
// round-to-nearest-even fp32 -> bf16
__device__ __forceinline__ unsigned f2bf(float x) {
    unsigned u = __builtin_bit_cast(unsigned, x);
    return (u + 0x7FFFu + ((u >> 16) & 1u)) >> 16;
}
__device__ __forceinline__ short8 pack_bf16x8(float4 a, float4 b) {
    union { unsigned u[4]; short8 s; } r;
    r.u[0] = f2bf(a.x) | (f2bf(a.y) << 16);
    r.u[1] = f2bf(a.z) | (f2bf(a.w) << 16);
    r.u[2] = f2bf(b.x) | (f2bf(b.y) << 16);
    r.u[3] = f2bf(b.z) | (f2bf(b.w) << 16);
    return r.s;
}

// ---- prep (1 block): level-prefix Pl, len-desc perm, coef, W bf16 fragments ----
__global__ __launch_bounds__(256) void nhll_prep(
    const int*   __restrict__ lens,     // [B]
    const float* __restrict__ ttime,    // [B]
    const float* __restrict__ W,        // [H, K]
    int*   __restrict__ Pl,             // [L+1]
    int*   __restrict__ perm,           // [B]
    float* __restrict__ coef,           // [B]
    uint4* __restrict__ wfrag)          // [2][8][64] bf16 B-fragments
{
    __shared__ int lens_s[BB];
    __shared__ int cnt_s[LL];
    const int tid = threadIdx.x;

    if (tid < BB) lens_s[tid] = lens[tid];
    __syncthreads();

    if (tid < BB) {
        const int ln = lens_s[tid];
        coef[tid] = ttime[tid] / (float)ln;
        int rk = 0;
        for (int b2 = 0; b2 < BB; ++b2) {
            const int l2 = lens_s[b2];
            rk += (l2 > ln) || (l2 == ln && b2 < tid);
        }
        perm[rk] = tid;                  // sorted by len descending (stable)
    }
    // cnt(l) = #{b : len_b > l}
    for (int l = tid; l < LL; l += 256) {
        int c = 0;
        for (int b = 0; b < BB; ++b) c += (lens_s[b] > l);
        cnt_s[l] = c;
    }
    __syncthreads();
    // exclusive prefix over levels (wave 0, 32 chunks of 64)
    if (tid < 64) {
        int carry = 0;
        if (tid == 0) Pl[0] = 0;
        for (int ch = 0; ch < LL / 64; ++ch) {
            int s = cnt_s[ch * 64 + tid];
#pragma unroll
            for (int mm = 1; mm < 64; mm <<= 1) {
                const int t = __shfl_up(s, mm, 64);
                if (tid >= mm) s += t;
            }
            Pl[ch * 64 + tid + 1] = carry + s;
            carry += __shfl(s, 63, 64);
        }
    }
    // W fragments: wfrag[n*512 + c*64 + lane], lane=(g,m): W[(32c+8g+j)*K + 16n + m]
    for (int idx = tid; idx < 1024; idx += 256) {
        const int n = idx >> 9, rem = idx & 511, c = rem >> 6, ln2 = rem & 63;
        const int g = ln2 >> 4, m = ln2 & 15;
        float a[8];
#pragma unroll
        for (int j = 0; j < 8; ++j) a[j] = W[(32 * c + 8 * g + j) * KK + 16 * n + m];
        wfrag[idx] = make_uint4(f2bf(a[0]) | (f2bf(a[1]) << 16),
                                f2bf(a[2]) | (f2bf(a[3]) << 16),
                                f2bf(a[4]) | (f2bf(a[5]) << 16),
                                f2bf(a[6]) | (f2bf(a[7]) << 16));
    }
}

// ---- main: 16 flat rows per wave-tile, l-major (memory-order) enumeration,
//      direct-to-fragment loads, W fragments from precomputed global ----
__global__ __launch_bounds__(256, 4) void nhll_main(
    const int*   __restrict__ events,   // [B, L]
    const float* __restrict__ hidden,   // [L, B, H]
    const float* __restrict__ cell,     // [L, B, H]
    const float* __restrict__ ctarg,    // [L, B, H]
    const float* __restrict__ outp,     // [L, B, H]
    const float* __restrict__ decay,    // [L, B, H]
    const float* __restrict__ simt,     // [L, B]
    const float* __restrict__ bias,     // [K]
    const int*   __restrict__ Pl_g,     // [L+1]
    const int*   __restrict__ perm_g,   // [B]
    const float* __restrict__ coef_g,   // [B]
    const uint4* __restrict__ wfrag,    // [2][8][64]
    float*       __restrict__ partial)  // [NB]
{
    __shared__ int   Pl[LL + 1];        // 8196 B
    __shared__ int   perm_s[BB];
    __shared__ float coef_s[BB];
    __shared__ float wacc[WPB];

    const int tid  = threadIdx.x;
    const int lane = tid & 63;
    const int q    = tid >> 6;
    const int g    = lane >> 4;     // h-octet within K-chunk
    const int m    = lane & 15;     // A-row / C-col index

    for (int i = tid; i < LL + 1; i += 256) Pl[i] = Pl_g[i];
    if (tid < BB) { perm_s[tid] = perm_g[tid]; coef_s[tid] = coef_g[tid]; }
    __syncthreads();

    // W^T B-fragments: 16 coalesced dwordx4 loads
    short8 w0f[8], w1f[8];
#pragma unroll
    for (int c = 0; c < 8; ++c) {
        w0f[c] = __builtin_bit_cast(short8, wfrag[c * 64 + lane]);
        w1f[c] = __builtin_bit_cast(short8, wfrag[512 + c * 64 + lane]);
    }
    const float b_lo = bias[m];
    const float b_hi = bias[16 + m];

    const int T      = Pl[LL];
    const int ntiles = (T + 15) >> 4;
    float acc = 0.f;

    for (int tile = blockIdx.x * WPB + q; tile < ntiles; tile += NB * WPB) {
        // lane owns flat row i (l-major): same l-neighborhood => contiguous memory
        int i = tile * 16 + m;
        const int valid = (i < T) ? 1 : 0;
        if (!valid) i = T - 1;                    // clamp; masked below
        int lo = 0, hi = LL;                      // search Pl[0..L]
#pragma unroll
        for (int s = 0; s < 11; ++s) {
            const int mid = (lo + hi) >> 1;
            if (Pl[mid] <= i) lo = mid; else hi = mid;
        }
        const int   l    = lo;
        const int   b    = perm_s[i - Pl[l]];     // j-th longest batch, len_b > l
        const int   r    = l * BB + b;
        const float st   = simt[r];
        const float coef = valid ? coef_s[b] : 0.f;
        const int   e    = events[b * LL + l + 1];   // l+1 <= len <= 2046

        const int base = r * HH + 8 * g;
        const float* ph = hidden + base;
        const float* pc = cell   + base;
        const float* pt = ctarg  + base;
        const float* po = outp   + base;
        const float* pd = decay  + base;

        f32x4 Cv0 = {0.f,0.f,0.f,0.f}, Cv1 = {0.f,0.f,0.f,0.f};
        f32x4 Ch0 = {0.f,0.f,0.f,0.f}, Ch1 = {0.f,0.f,0.f,0.f};

#pragma unroll
        for (int c = 0; c < 8; ++c) {
            const float4 h0 = *(const float4*)(ph + 32 * c);
            const float4 h1 = *(const float4*)(ph + 32 * c + 4);
            const float4 c0 = *(const float4*)(pc + 32 * c);
            const float4 c1 = *(const float4*)(pc + 32 * c + 4);
            const float4 t0 = *(const float4*)(pt + 32 * c);
            const float4 t1 = *(const float4*)(pt + 32 * c + 4);
            const float4 o0 = *(const float4*)(po + 32 * c);
            const float4 o1 = *(const float4*)(po + 32 * c + 4);
            const float4 d0 = *(const float4*)(pd + 32 * c);
            const float4 d1 = *(const float4*)(pd + 32 * c + 4);

            float4 v0, v1;
            {
                float cs, e2;
                cs = t0.x + (c0.x - t0.x) * __expf(-d0.x * st); e2 = __expf(2.f * cs); v0.x = o0.x * ((e2 - 1.f) / (e2 + 1.f));
                cs = t0.y + (c0.y - t0.y) * __expf(-d0.y * st); e2 = __expf(2.f * cs); v0.y = o0.y * ((e2 - 1.f) / (e2 + 1.f));
                cs = t0.z + (c0.z - t0.z) * __expf(-d0.z * st); e2 = __expf(2.f * cs); v0.z = o0.z * ((e2 - 1.f) / (e2 + 1.f));
                cs = t0.w + (c0.w - t0.w) * __expf(-d0.w * st); e2 = __expf(2.f * cs); v0.w = o0.w * ((e2 - 1.f) / (e2 + 1.f));
                cs = t1.x + (c1.x - t1.x) * __expf(-d1.x * st); e2 = __expf(2.f * cs); v1.x = o1.x * ((e2 - 1.f) / (e2 + 1.f));
                cs = t1.y + (c1.y - t1.y) * __expf(-d1.y * st); e2 = __expf(2.f * cs); v1.y = o1.y * ((e2 - 1.f) / (e2 + 1.f));
                cs = t1.z + (c1.z - t1.z) * __expf(-d1.z * st); e2 = __expf(2.f * cs); v1.z = o1.z * ((e2 - 1.f) / (e2 + 1.f));
                cs = t1.w + (c1.w - t1.w) * __expf(-d1.w * st); e2 = __expf(2.f * cs); v1.w = o1.w * ((e2 - 1.f) / (e2 + 1.f));
            }
            const short8 av = pack_bf16x8(v0, v1);
            const short8 ah = pack_bf16x8(h0, h1);
            Cv0 = __builtin_amdgcn_mfma_f32_16x16x32_bf16(av, w0f[c], Cv0, 0, 0, 0);
            Cv1 = __builtin_amdgcn_mfma_f32_16x16x32_bf16(av, w1f[c], Cv1, 0, 0, 0);
            Ch0 = __builtin_amdgcn_mfma_f32_16x16x32_bf16(ah, w0f[c], Ch0, 0, 0, 0);
            Ch1 = __builtin_amdgcn_mfma_f32_16x16x32_bf16(ah, w1f[c], Ch1, 0, 0, 0);
        }

        // ---- term 2: row = 4g+reg, col = m; sum softplus over 32 cols ----
        float sp[4];
#pragma unroll
        for (int reg = 0; reg < 4; ++reg)
            sp[reg] = softplus_f(Cv0[reg] + b_lo) + softplus_f(Cv1[reg] + b_hi);
#pragma unroll
        for (int mk = 1; mk <= 8; mk <<= 1) {
#pragma unroll
            for (int reg = 0; reg < 4; ++reg) sp[reg] += __shfl_xor(sp[reg], mk, 64);
        }
        float t2 = 0.f;
#pragma unroll
        for (int reg = 0; reg < 4; ++reg) {
            const float cf = __shfl(coef, 4 * g + reg, 64);   // coef of row 4g+reg
            t2 += cf * sp[reg];
        }
        if (m == 0) acc += t2;

        // ---- term 1: hidden-row rr gathered at column e_rr ----
        float kv = 0.f, kb = 0.f;
#pragma unroll
        for (int rr = 0; rr < 16; ++rr) {
            const int   er   = __shfl(e, rr, 64);             // e of row rr
            const float cand = (er < 16) ? Ch0[rr & 3] : Ch1[rr & 3];
            const float val  = __shfl(cand, ((rr >> 2) << 4) + (er & 15), 64);
            const float bsel = (er < 16) ? b_lo : b_hi;
            const float be   = __shfl(bsel, er & 15, 64);
            if (lane == rr) { kv = val; kb = be; }
        }
        if (lane < 16 && valid)
            acc -= __logf(softplus_f(kv + kb));
    }

    // wave reduce + block reduce
#pragma unroll
    for (int mk = 1; mk < 64; mk <<= 1) acc += __shfl_xor(acc, mk, 64);
    if (lane == 0) wacc[q] = acc;
    __syncthreads();
    if (tid == 0) partial[blockIdx.x] = wacc[0] + wacc[1] + wacc[2] + wacc[3];
}

// Output: single float32 scalar.
__global__ __launch_bounds__(256) void nhll_finalize(
    const float* __restrict__ partial, float* __restrict__ out)
{
    __shared__ float red[4];
    float s = 0.f;
    for (int i = threadIdx.x; i < NB; i += 256) s += partial[i];
    for (int mk = 1; mk < 64; mk <<= 1) s += __shfl_xor(s, mk, 64);
    if ((threadIdx.x & 63) == 0) red[threadIdx.x >> 6] = s;
    __syncthreads();
    if (threadIdx.x == 0)
        out[0] = red[0] + red[1] + red[2] + red[3];
}

extern "C" void kernel_launch(void* const* d_in, const int* in_sizes, int n_in,
                              void* d_out, int out_size, void* d_ws, size_t ws_size,
                              hipStream_t stream) {
    const int*   events = (const int*)  d_in[0];   // event_seqs  [B,L] int32
    const int*   lens   = (const int*)  d_in[1];   // seqs_length [B]   int32
    const float* ttime  = (const float*)d_in[2];   // total_time  [B]
    const float* hidden = (const float*)d_in[3];   // [L,B,H]
    const float* cell   = (const float*)d_in[4];   // [L,B,H]
    const float* ctarg  = (const float*)d_in[5];   // [L,B,H]
    const float* outp   = (const float*)d_in[6];   // [L,B,H]
    const float* decay  = (const float*)d_in[7];   // [L,B,H]
    const float* simt   = (const float*)d_in[8];   // [L,B]
    const float* W      = (const float*)d_in[9];   // [H,K]
    const float* bias   = (const float*)d_in[10];  // [K]

    // workspace layout (bytes): Pl [0,8196) pad->8448 | perm 8448 | coef 8704 |
    // wfrag 9216 (16384) | partial 25600 (NB*4)
    char*  ws    = (char*)d_ws;
    int*   Pl    = (int*)  (ws + 0);
    int*   perm  = (int*)  (ws + 8448);
    float* coef  = (float*)(ws + 8704);
    uint4* wfrag = (uint4*)(ws + 9216);
    float* part  = (float*)(ws + 25600);
    float* out   = (float*)d_out;

    nhll_prep<<<1, 256, 0, stream>>>(lens, ttime, W, Pl, perm, coef, wfrag);
    nhll_main<<<NB, 256, 0, stream>>>(events, hidden, cell, ctarg, outp, decay,
                                      simt, bias, Pl, perm, coef, wfrag, part);
    nhll_finalize<<<1, 256, 0, stream>>>(part, out);
}

// Round 9
// 68.353 us; speedup vs baseline: 2.0108x; 2.0108x over previous
//
#include <hip/hip_runtime.h>

// Problem constants (match reference): B=64, L=2048, H=256, K=32
#define LL 2048
#define BB 64
#define HH 256
#define KK 32

#define NB  768    // 3 blocks/CU (LDS-limited: ~49.5 KB/block)
#define WPB 4      // waves per block

typedef __attribute__((ext_vector_type(8))) short  short8;   // 8 bf16 (4 VGPRs)
typedef __attribute__((ext_vector_type(4))) float  f32x4;

__device__ __forceinline__ float softplus_f(float x) {
    return x > 20.f ? x : __logf(1.f + __expf(x));
}
// round-to-nearest-even fp32 -> bf16
__device__ __forceinline__ unsigned f2bf(float x) {
    unsigned u = __builtin_bit_cast(unsigned, x);
    return (u + 0x7FFFu + ((u >> 16) & 1u)) >> 16;
}

struct RowT { float4 h, c, t, o, d; };

// 8 flat rows per wave-tile. Per-wave LDS A-tile[16][256]bf16: rows 0-7 = v,
// rows 8-15 = hidden (XOR-swizzled). Staging loop runs a 3-deep register
// rotation: rows j+1..j+3 loads in flight while row j computes/stores.
// MFMA C[16][32]: rows 0-7 v-dots (term2), 8-15 h-dots (term1).
__global__ __launch_bounds__(256, 3) void nhll_main(
    const int*   __restrict__ events,   // [B, L]
    const int*   __restrict__ lens,     // [B]
    const float* __restrict__ ttime,    // [B]
    const float* __restrict__ hidden,   // [L, B, H]
    const float* __restrict__ cell,     // [L, B, H]
    const float* __restrict__ ctarg,    // [L, B, H]
    const float* __restrict__ outp,     // [L, B, H]
    const float* __restrict__ decay,    // [L, B, H]
    const float* __restrict__ simt,     // [L, B]
    const float* __restrict__ W,        // [H, K]
    const float* __restrict__ bias,     // [K]
    float*       __restrict__ partial)  // [NB]
{
    __shared__ __align__(16) char  WTs[KK * HH * 2];        // 16 KB W^T bf16, swizzled
    __shared__ __align__(16) char  Als[WPB][16 * HH * 2];   // 8 KB per wave
    __shared__ int   pfx[BB + 1];
    __shared__ float coef_s[BB];
    __shared__ float wacc[WPB];

    const int tid  = threadIdx.x;
    const int lane = tid & 63;
    const int q    = tid >> 6;
    const int g    = lane >> 4;     // h-octet within K-chunk
    const int m    = lane & 15;     // A-row / C-col index

    // ---- one-time: W^T bf16 into LDS (row k, position h=tid, swizzled) ----
    {
        const float* wrow = &W[tid * KK];
#pragma unroll
        for (int k = 0; k < KK; ++k) {
            const int byte = (k * 512 + tid * 2) ^ ((k & 7) << 4);
            *(unsigned short*)(WTs + byte) = (unsigned short)f2bf(wrow[k]);
        }
    }
    if (tid < BB) {                 // wave 0: scan lens -> prefix sums
        const int ln = lens[tid];
        coef_s[tid] = ttime[tid] / (float)ln;
        int s = ln;
#pragma unroll
        for (int mm = 1; mm < 64; mm <<= 1) {
            const int t = __shfl_up(s, mm, 64);
            if (lane >= mm) s += t;
        }
        pfx[tid + 1] = s;
        if (tid == 0) pfx[0] = 0;
    }
    __syncthreads();

    const float b_lo = bias[m];
    const float b_hi = bias[16 + m];
    const int   T      = pfx[BB];
    const int   ntiles = (T + 7) >> 3;
    char* Aw = Als[q];
    float acc = 0.f;

    for (int tile = blockIdx.x * WPB + q; tile < ntiles; tile += NB * WPB) {
        // ---- parallel metadata: lane j (j = lane&7) owns flat row tile*8+j ----
        int i = tile * 8 + (lane & 7);
        const int valid = (i < T) ? 1 : 0;
        if (!valid) i = T - 1;                    // clamp; masked below
        int lo = 0, hi = BB;
#pragma unroll
        for (int s = 0; s < 6; ++s) {
            const int mid = (lo + hi) >> 1;
            if (pfx[mid] <= i) lo = mid; else hi = mid;
        }
        const int   b    = lo;
        const int   l    = i - pfx[b];
        const int   r    = l * BB + b;
        const float st   = simt[r];
        const float coef = valid ? coef_s[b] : 0.f;
        const int   e    = events[b * LL + l + 1];   // l+1 <= len <= 2046

        int   rs[8]; float ss[8];
#pragma unroll
        for (int j = 0; j < 8; ++j) {
            rs[j] = __shfl(r, j, 64);
            ss[j] = __shfl(st, j, 64);
        }

        // ---- staging with 3-deep load rotation ----
        auto LD = [&](int rr_) -> RowT {
            const int base = rr_ * HH + lane * 4;
            RowT x;
            x.h = *(const float4*)(hidden + base);
            x.c = *(const float4*)(cell   + base);
            x.t = *(const float4*)(ctarg  + base);
            x.o = *(const float4*)(outp   + base);
            x.d = *(const float4*)(decay  + base);
            return x;
        };
        auto ST = [&](int j, const RowT& R, float stv) {
            float4 v;
            float cs, e2;
            cs = R.t.x + (R.c.x - R.t.x) * __expf(-R.d.x * stv); e2 = __expf(2.f * cs); v.x = R.o.x * ((e2 - 1.f) / (e2 + 1.f));
            cs = R.t.y + (R.c.y - R.t.y) * __expf(-R.d.y * stv); e2 = __expf(2.f * cs); v.y = R.o.y * ((e2 - 1.f) / (e2 + 1.f));
            cs = R.t.z + (R.c.z - R.t.z) * __expf(-R.d.z * stv); e2 = __expf(2.f * cs); v.z = R.o.z * ((e2 - 1.f) / (e2 + 1.f));
            cs = R.t.w + (R.c.w - R.t.w) * __expf(-R.d.w * stv); e2 = __expf(2.f * cs); v.w = R.o.w * ((e2 - 1.f) / (e2 + 1.f));
            const int swz = (j & 7) << 4;      // (8+j)&7 == j&7
            *(uint2*)(Aw + ((j * 512 + lane * 8) ^ swz)) =
                make_uint2(f2bf(v.x) | (f2bf(v.y) << 16), f2bf(v.z) | (f2bf(v.w) << 16));
            *(uint2*)(Aw + (((8 + j) * 512 + lane * 8) ^ swz)) =
                make_uint2(f2bf(R.h.x) | (f2bf(R.h.y) << 16), f2bf(R.h.z) | (f2bf(R.h.w) << 16));
        };

        RowT buf[3];
        buf[0] = LD(rs[0]); buf[1] = LD(rs[1]); buf[2] = LD(rs[2]);
#pragma unroll
        for (int j = 0; j < 8; ++j) {
            ST(j, buf[j % 3], ss[j]);
            if (j + 3 < 8) buf[j % 3] = LD(rs[j + 3]);
        }

        // ---- MFMA: C[16][32], A and both W-tiles from LDS ----
        f32x4 C0 = {0.f,0.f,0.f,0.f}, C1 = {0.f,0.f,0.f,0.f};
        const int abase = m * 512 + 16 * g;
        const int swz   = (m & 7) << 4;
#pragma unroll
        for (int c = 0; c < 8; ++c) {
            const short8 a  = *(const short8*)(Aw  + ((abase + 64 * c) ^ swz));
            const short8 w0 = *(const short8*)(WTs + ((abase + 64 * c) ^ swz));
            const short8 w1 = *(const short8*)(WTs + ((abase + 8192 + 64 * c) ^ swz));
            C0 = __builtin_amdgcn_mfma_f32_16x16x32_bf16(a, w0, C0, 0, 0, 0);
            C1 = __builtin_amdgcn_mfma_f32_16x16x32_bf16(a, w1, C1, 0, 0, 0);
        }

        // ---- term 2: C rows 0-7 (g<2), row = 4g+reg, col = m ----
        float sp[4];
#pragma unroll
        for (int reg = 0; reg < 4; ++reg)
            sp[reg] = softplus_f(C0[reg] + b_lo) + softplus_f(C1[reg] + b_hi);
#pragma unroll
        for (int mk = 1; mk <= 8; mk <<= 1) {
#pragma unroll
            for (int reg = 0; reg < 4; ++reg) sp[reg] += __shfl_xor(sp[reg], mk, 64);
        }
        float t2 = 0.f;
#pragma unroll
        for (int reg = 0; reg < 4; ++reg) {
            const float cf = __shfl(coef, 4 * g + reg, 64);  // coef of flat row 4g+reg
            t2 += cf * sp[reg];
        }
        if (m == 0 && g < 2) acc += t2;

        // ---- term 1: C rows 8-15 (g=2,3) gathered at column e ----
        float kv = 0.f, kb = 0.f;
#pragma unroll
        for (int rr = 0; rr < 8; ++rr) {
            const int   er   = __shfl(e, rr, 64);            // e of flat row rr
            const float cand = (er < 16) ? C0[rr & 3] : C1[rr & 3];
            const float val  = __shfl(cand, 32 + ((rr >> 2) << 4) + (er & 15), 64);
            const float bsel = (er < 16) ? b_lo : b_hi;
            const float be   = __shfl(bsel, er & 15, 64);
            if (lane == rr) { kv = val; kb = be; }
        }
        if (lane < 8 && valid)
            acc -= __logf(softplus_f(kv + kb));
    }

    // wave reduce + block reduce
#pragma unroll
    for (int mk = 1; mk < 64; mk <<= 1) acc += __shfl_xor(acc, mk, 64);
    if (lane == 0) wacc[q] = acc;
    __syncthreads();
    if (tid == 0) partial[blockIdx.x] = wacc[0] + wacc[1] + wacc[2] + wacc[3];
}

// Output: single float32 scalar.
__global__ __launch_bounds__(256) void nhll_finalize(
    const float* __restrict__ partial, float* __restrict__ out)
{
    __shared__ float red[4];
    float s = 0.f;
    for (int i = threadIdx.x; i < NB; i += 256) s += partial[i];
    for (int mk = 1; mk < 64; mk <<= 1) s += __shfl_xor(s, mk, 64);
    if ((threadIdx.x & 63) == 0) red[threadIdx.x >> 6] = s;
    __syncthreads();
    if (threadIdx.x == 0)
        out[0] = red[0] + red[1] + red[2] + red[3];
}

extern "C" void kernel_launch(void* const* d_in, const int* in_sizes, int n_in,
                              void* d_out, int out_size, void* d_ws, size_t ws_size,
                              hipStream_t stream) {
    const int*   events = (const int*)  d_in[0];   // event_seqs  [B,L] int32
    const int*   lens   = (const int*)  d_in[1];   // seqs_length [B]   int32
    const float* ttime  = (const float*)d_in[2];   // total_time  [B]
    const float* hidden = (const float*)d_in[3];   // [L,B,H]
    const float* cell   = (const float*)d_in[4];   // [L,B,H]
    const float* ctarg  = (const float*)d_in[5];   // [L,B,H]
    const float* outp   = (const float*)d_in[6];   // [L,B,H]
    const float* decay  = (const float*)d_in[7];   // [L,B,H]
    const float* simt   = (const float*)d_in[8];   // [L,B]
    const float* W      = (const float*)d_in[9];   // [H,K]
    const float* bias   = (const float*)d_in[10];  // [K]

    float* part = (float*)d_ws;                    // NB floats
    float* out  = (float*)d_out;

    nhll_main<<<NB, 256, 0, stream>>>(events, lens, ttime, hidden, cell, ctarg,
                                      outp, decay, simt, W, bias, part);
    nhll_finalize<<<1, 256, 0, stream>>>(part, out);
}